// Round 4
// baseline (39.056 us; speedup 1.0000x reference)
//
#include <hip/hip_runtime.h>

#define TPB 256
#define WPB 4                    // waves per block
typedef float v4f __attribute__((ext_vector_type(4)));

#define NTS(v, p)  __builtin_nontemporal_store((v), (p))
#define WBAR()     __builtin_amdgcn_wave_barrier()

// One Euler-Maruyama step with closed-form polar (Rodrigues) retraction.
// x <- x * (I + c1*S + c2*S^2), S = hs*(x^T e - e^T x) skew, axial (A,Bv,Cv).
__device__ __forceinline__ void so3_step(float x[9], const float e[9], float hs) {
    float wa = 0.f, wb = 0.f, wc = 0.f;
    #pragma unroll
    for (int k = 0; k < 3; ++k) {
        const float xk0 = x[k*3+0], xk1 = x[k*3+1], xk2 = x[k*3+2];
        const float ek0 = e[k*3+0], ek1 = e[k*3+1], ek2 = e[k*3+2];
        wa += xk2*ek1 - xk1*ek2;
        wb += xk0*ek2 - xk2*ek0;
        wc += xk1*ek0 - xk0*ek1;
    }
    const float A  = hs * wa;
    const float Bv = hs * wb;
    const float Cv = hs * wc;

    const float th2 = A*A + Bv*Bv + Cv*Cv;
    const float c1  = rsqrtf(1.0f + th2);
    const float c2  = c1*c1 / (1.0f + c1);   // (1 - c1)/th2, stable at th2 -> 0

    const float q00 = 1.0f - c2*(Bv*Bv + Cv*Cv);
    const float q11 = 1.0f - c2*(A*A  + Cv*Cv);
    const float q22 = 1.0f - c2*(A*A  + Bv*Bv);
    const float q01 = c2*A*Bv  - c1*Cv;
    const float q10 = c2*A*Bv  + c1*Cv;
    const float q02 = c2*A*Cv  + c1*Bv;
    const float q20 = c2*A*Cv  - c1*Bv;
    const float q12 = c2*Bv*Cv - c1*A;
    const float q21 = c2*Bv*Cv + c1*A;

    #pragma unroll
    for (int r = 0; r < 3; ++r) {
        const float a0 = x[r*3+0], a1 = x[r*3+1], a2 = x[r*3+2];
        x[r*3+0] = a0*q00 + a1*q10 + a2*q20;
        x[r*3+1] = a0*q01 + a1*q11 + a2*q21;
        x[r*3+2] = a0*q02 + a1*q12 + a2*q22;
    }
}

__global__ __launch_bounds__(TPB) void brownian_so3_kernel(
    const float* __restrict__ x0,
    const float* __restrict__ t,
    const float* __restrict__ noise,
    float* __restrict__ out,
    int B, int steps)
{
    // 2 buffers x 4 waves x 144 float4 (2304 B per wave tile) = 18432 B.
    __shared__ v4f lds[2][WPB][144];

    const int tid  = threadIdx.x;
    const int wave = tid >> 6;
    const int lane = tid & 63;
    const int sbase = (blockIdx.x * WPB + wave) * 64;   // wave's first sample
    const int b     = sbase + lane;
    const long fbase  = (long)sbase * 9;                // float offset of wave tile
    const long stride = (long)B * 9;

    const float tv = t[b];

    v4f* buf0 = &lds[0][wave][0];
    v4f* buf1 = &lds[1][wave][0];
    const float* f0 = (const float*)buf0;
    const float* f1 = (const float*)buf1;

    // ---- Stage x0 through wave-private LDS (aligned coalesced loads) ----
    {
        const v4f* src = (const v4f*)(x0 + fbase);
        buf0[lane]      = src[lane];
        buf0[lane + 64] = src[lane + 64];
        if (lane < 16) buf0[lane + 128] = src[lane + 128];
    }
    WBAR();
    float x[9];
    #pragma unroll
    for (int j = 0; j < 9; ++j) x[j] = f0[lane*9 + j];
    WBAR();   // buf0 overwritten with noise tile 0 below (same-wave DS is in-order)

    const float hs = 0.5f * sqrtf(tv / (float)steps);

    // ---- Register double-buffer A/B, prefetch distance 2 ----
    v4f A0, A1, A2, B0, B1, B2;
    A2 = (v4f)0.f; B2 = (v4f)0.f; B0 = (v4f)0.f; B1 = (v4f)0.f;
    {
        const v4f* src = (const v4f*)(noise + fbase);             // tile 0 -> A
        A0 = src[lane]; A1 = src[lane + 64];
        if (lane < 16) A2 = src[lane + 128];
    }
    if (steps > 1) {
        const v4f* src = (const v4f*)(noise + stride + fbase);    // tile 1 -> B
        B0 = src[lane]; B1 = src[lane + 64];
        if (lane < 16) B2 = src[lane + 128];
    }
    // tile 0 -> buf0
    buf0[lane] = A0; buf0[lane + 64] = A1;
    if (lane < 16) buf0[lane + 128] = A2;
    if (steps > 2) {
        const v4f* src = (const v4f*)(noise + 2*stride + fbase);  // tile 2 -> A
        A0 = src[lane]; A1 = src[lane + 64];
        if (lane < 16) A2 = src[lane + 128];
    }

    float e[9];
    int s = 0;
    for (; s + 1 < steps; s += 2) {
        // ---- even step s: tile s lives in buf0 ----
        {   // write tile s+1 (regs B) -> buf1
            buf1[lane] = B0; buf1[lane + 64] = B1;
            if (lane < 16) buf1[lane + 128] = B2;
        }
        if (s + 3 < steps) {   // tile s+3 -> B (2 steps of flight)
            const v4f* src = (const v4f*)(noise + (long)(s+3)*stride + fbase);
            B0 = src[lane]; B1 = src[lane + 64];
            if (lane < 16) B2 = src[lane + 128];
        }
        #pragma unroll
        for (int j = 0; j < 9; ++j) e[j] = f0[lane*9 + j];
        so3_step(x, e, hs);
        WBAR();

        // ---- odd step s+1: tile s+1 lives in buf1 ----
        if (s + 2 < steps) {   // write tile s+2 (regs A) -> buf0
            buf0[lane] = A0; buf0[lane + 64] = A1;
            if (lane < 16) buf0[lane + 128] = A2;
        }
        if (s + 4 < steps) {   // tile s+4 -> A
            const v4f* src = (const v4f*)(noise + (long)(s+4)*stride + fbase);
            A0 = src[lane]; A1 = src[lane + 64];
            if (lane < 16) A2 = src[lane + 128];
        }
        #pragma unroll
        for (int j = 0; j < 9; ++j) e[j] = f1[lane*9 + j];
        so3_step(x, e, hs);
        WBAR();
    }
    if (s < steps) {   // odd trailing step (not hit for steps=20)
        #pragma unroll
        for (int j = 0; j < 9; ++j) e[j] = f0[lane*9 + j];
        so3_step(x, e, hs);
    }

    // ---- Store via wave-private LDS transpose (aligned NT float4 stores) ----
    WBAR();
    {
        float* ob = (float*)buf0;
        #pragma unroll
        for (int j = 0; j < 9; ++j) ob[lane*9 + j] = x[j];
    }
    WBAR();
    {
        v4f* dst = (v4f*)(out + fbase);
        NTS(buf0[lane],      dst + lane);
        NTS(buf0[lane + 64], dst + lane + 64);
        if (lane < 16) NTS(buf0[lane + 128], dst + lane + 128);
    }
}

extern "C" void kernel_launch(void* const* d_in, const int* in_sizes, int n_in,
                              void* d_out, int out_size, void* d_ws, size_t ws_size,
                              hipStream_t stream) {
    const float* x0    = (const float*)d_in[0];
    const float* t     = (const float*)d_in[1];
    const float* noise = (const float*)d_in[2];
    float* out = (float*)d_out;

    const int B     = in_sizes[0] / 9;
    const int steps = in_sizes[2] / in_sizes[0];

    const int grid = B / TPB;   // 262144 / 256 = 1024 blocks
    brownian_so3_kernel<<<grid, TPB, 0, stream>>>(x0, t, noise, out, B, steps);
}